// Round 1
// baseline (122.616 us; speedup 1.0000x reference)
//
#include <hip/hip_runtime.h>
#include <stdint.h>

#define NROWS 8192
#define DDIM  128
#define NCHUNK 8
#define CPC   1024            // columns per chunk
#define NTILE 8               // 128-wide tiles per chunk

#define LOG2E 1.4426950408889634f
#define LN2   0.6931471805599453f
#define SCALE (10.0f * LOG2E) // 1/temperature in log2 domain

typedef __bf16 bf16x4 __attribute__((ext_vector_type(4)));
typedef __bf16 bf16x8 __attribute__((ext_vector_type(8)));
typedef float  f32x4  __attribute__((ext_vector_type(4)));

// ---------------------------------------------------------------- convert t -> bf16
__global__ void convert_kernel(const float* __restrict__ t, __bf16* __restrict__ tb) {
    int idx = blockIdx.x * 256 + threadIdx.x;          // one float4 per thread
    float4 v = reinterpret_cast<const float4*>(t)[idx];
    bf16x4 o;
    o[0] = (__bf16)v.x; o[1] = (__bf16)v.y; o[2] = (__bf16)v.z; o[3] = (__bf16)v.w;
    reinterpret_cast<bf16x4*>(tb)[idx] = o;
}

// ------------------------------------------------- exact fp32 per-row dot products
// s10[i]  = SCALE * (q_i . q_{j_i})            (log2 units)
// num[i]  = 10 * | q_i.q_{j_i} - t_i.t_{j_i} | (natural units)
__global__ void dots_kernel(const float* __restrict__ q, const float* __restrict__ t,
                            const int* __restrict__ jidx,
                            float* __restrict__ s10, float* __restrict__ num) {
    int w    = (blockIdx.x * 256 + threadIdx.x) >> 6;  // one wave per row
    int lane = threadIdx.x & 63;
    int i = w;
    int j = jidx[i];
    float2 qa = reinterpret_cast<const float2*>(q + (size_t)i * DDIM)[lane];
    float2 qb = reinterpret_cast<const float2*>(q + (size_t)j * DDIM)[lane];
    float2 ta = reinterpret_cast<const float2*>(t + (size_t)i * DDIM)[lane];
    float2 tc = reinterpret_cast<const float2*>(t + (size_t)j * DDIM)[lane];
    float dq = qa.x * qb.x + qa.y * qb.y;
    float dt = ta.x * tc.x + ta.y * tc.y;
    #pragma unroll
    for (int off = 32; off; off >>= 1) {
        dq += __shfl_xor(dq, off);
        dt += __shfl_xor(dt, off);
    }
    if (lane == 0) {
        s10[i] = SCALE * dq;
        num[i] = 10.0f * fabsf(dq - dt);
    }
}

// ---------------------------------------------- fused t@t^T + online LSE (bf16 MFMA)
// grid: 64 stripes x 8 chunks. block: 256 thr (4 waves). wave: 32 rows x 128 cols.
__global__ __launch_bounds__(256, 2) void lse_kernel(
    const __bf16* __restrict__ tb, const float* __restrict__ s10,
    float* __restrict__ Pm, float* __restrict__ Ps) {
    __shared__ __bf16 At[128 * 128];
    __shared__ __bf16 Bt[128 * 128];

    const int tid    = threadIdx.x;
    const int stripe = blockIdx.x >> 3;
    const int chunk  = blockIdx.x & 7;
    const int row0   = stripe * 128;
    const int col0   = chunk * CPC;

    // ---- stage A (row stripe of t), pre-swizzled source -> linear LDS writes
    {
        const uint4* src = reinterpret_cast<const uint4*>(tb + (size_t)row0 * DDIM);
        uint4* dst = reinterpret_cast<uint4*>(At);
        #pragma unroll
        for (int it = 0; it < 8; ++it) {
            int idx = it * 256 + tid;
            int r = idx >> 4;
            int c = idx & 15;
            dst[idx] = src[r * 16 + (c ^ (r & 7))];
        }
    }

    const int lane = tid & 63;
    const int wid  = tid >> 6;
    const int g    = lane >> 4;    // 16-lane group (k-group for A/B, row-group for D)
    const int lr   = lane & 15;    // row within A-frag / col within B,D-frag
    const int swz  = (lr & 7) << 4;

    // s10 for this lane's 8 output rows (replicated over the 16-lane group)
    float sS[2][4];
    #pragma unroll
    for (int mf = 0; mf < 2; ++mf)
        #pragma unroll
        for (int r = 0; r < 4; ++r)
            sS[mf][r] = s10[row0 + wid * 32 + mf * 16 + g * 4 + r];

    float mrun[2][4], srun[2][4];
    #pragma unroll
    for (int mf = 0; mf < 2; ++mf)
        #pragma unroll
        for (int r = 0; r < 4; ++r) { mrun[mf][r] = -1e30f; srun[mf][r] = 0.0f; }

    const char* Ab = reinterpret_cast<const char*>(At);
    const char* Bb = reinterpret_cast<const char*>(Bt);

    for (int tile = 0; tile < NTILE; ++tile) {
        __syncthreads();   // previous tile fully consumed
        // ---- stage B tile
        {
            const uint4* src = reinterpret_cast<const uint4*>(
                tb + (size_t)(col0 + tile * 128) * DDIM);
            uint4* dst = reinterpret_cast<uint4*>(Bt);
            #pragma unroll
            for (int it = 0; it < 8; ++it) {
                int idx = it * 256 + tid;
                int r = idx >> 4;
                int c = idx & 15;
                dst[idx] = src[r * 16 + (c ^ (r & 7))];
            }
        }
        __syncthreads();

        // ---- 128x128x128 MFMA
        f32x4 acc[2][8];
        #pragma unroll
        for (int mf = 0; mf < 2; ++mf)
            #pragma unroll
            for (int nf = 0; nf < 8; ++nf)
                acc[mf][nf] = (f32x4){0.f, 0.f, 0.f, 0.f};

        #pragma unroll
        for (int kk = 0; kk < 4; ++kk) {
            bf16x8 af[2];
            #pragma unroll
            for (int mf = 0; mf < 2; ++mf) {
                int row = wid * 32 + mf * 16 + lr;
                int off = row * 256 + ((g * 16 + kk * 64) ^ swz);
                af[mf] = *reinterpret_cast<const bf16x8*>(Ab + off);
            }
            bf16x8 bfr[8];
            #pragma unroll
            for (int nf = 0; nf < 8; ++nf) {
                int row = nf * 16 + lr;
                int off = row * 256 + ((g * 16 + kk * 64) ^ swz);
                bfr[nf] = *reinterpret_cast<const bf16x8*>(Bb + off);
            }
            #pragma unroll
            for (int mf = 0; mf < 2; ++mf)
                #pragma unroll
                for (int nf = 0; nf < 8; ++nf)
                    acc[mf][nf] = __builtin_amdgcn_mfma_f32_16x16x32_bf16(
                        af[mf], bfr[nf], acc[mf][nf], 0, 0, 0);
        }

        // ---- online LSE epilogue (log2 domain, per-lane columns only)
        #pragma unroll
        for (int mf = 0; mf < 2; ++mf) {
            #pragma unroll
            for (int r = 0; r < 4; ++r) {
                float sv = sS[mf][r];
                float tv[8];
                #pragma unroll
                for (int nf = 0; nf < 8; ++nf)
                    tv[nf] = fabsf(fmaf(acc[mf][nf][r], -SCALE, sv));
                float tm = fmaxf(fmaxf(fmaxf(tv[0], tv[1]), fmaxf(tv[2], tv[3])),
                                 fmaxf(fmaxf(tv[4], tv[5]), fmaxf(tv[6], tv[7])));
                float m = mrun[mf][r], s = srun[mf][r];
                float nm = fmaxf(m, tm);
                s *= exp2f(m - nm);
                #pragma unroll
                for (int nf = 0; nf < 8; ++nf)
                    s += exp2f(tv[nf] - nm);
                mrun[mf][r] = nm;
                srun[mf][r] = s;
            }
        }
    }

    // ---- merge LSE state across the 16-lane column group, write partials
    #pragma unroll
    for (int mf = 0; mf < 2; ++mf) {
        #pragma unroll
        for (int r = 0; r < 4; ++r) {
            float m = mrun[mf][r], s = srun[mf][r];
            #pragma unroll
            for (int off = 1; off < 16; off <<= 1) {
                float om = __shfl_xor(m, off);
                float os = __shfl_xor(s, off);
                float nm = fmaxf(m, om);
                s = s * exp2f(m - nm) + os * exp2f(om - nm);
                m = nm;
            }
            if (lr == 0) {
                int row = row0 + wid * 32 + mf * 16 + g * 4 + r;
                Pm[row * 8 + chunk] = m;
                Ps[row * 8 + chunk] = s;
            }
        }
    }
}

// ------------------------------------------------------------- final reduction
__global__ void finalize_kernel(const float* __restrict__ Pm, const float* __restrict__ Ps,
                                const float* __restrict__ num, float* __restrict__ out) {
    int tid = threadIdx.x;
    float acc = 0.0f;
    for (int it = 0; it < NROWS / 256; ++it) {
        int row = it * 256 + tid;
        float M = -1e30f;
        #pragma unroll
        for (int c = 0; c < 8; ++c) M = fmaxf(M, Pm[row * 8 + c]);
        float S = 0.0f;
        #pragma unroll
        for (int c = 0; c < 8; ++c) S += Ps[row * 8 + c] * exp2f(Pm[row * 8 + c] - M);
        float L = LN2 * (M + log2f(S));
        acc += L - num[row];
    }
    __shared__ float red[256];
    red[tid] = acc;
    __syncthreads();
    for (int s2 = 128; s2 > 0; s2 >>= 1) {
        if (tid < s2) red[tid] += red[tid + s2];
        __syncthreads();
    }
    if (tid == 0) out[0] = red[0] / (float)NROWS;
}

extern "C" void kernel_launch(void* const* d_in, const int* in_sizes, int n_in,
                              void* d_out, int out_size, void* d_ws, size_t ws_size,
                              hipStream_t stream) {
    const float* q   = (const float*)d_in[0];
    const float* t   = (const float*)d_in[1];
    const int* jidx  = (const int*)d_in[3];   // d_in[2] = labels (== arange, unused)
    float* out       = (float*)d_out;

    char* ws   = (char*)d_ws;
    __bf16* tb = (__bf16*)ws;                                  // 2 MB
    float* s10 = (float*)(ws + (size_t)NROWS * DDIM * 2);
    float* num = s10 + NROWS;
    float* Pm  = num + NROWS;                                  // 8192*8 floats
    float* Ps  = Pm + NROWS * 8;

    hipLaunchKernelGGL(convert_kernel, dim3(NROWS * DDIM / 4 / 256), dim3(256), 0, stream,
                       t, tb);
    hipLaunchKernelGGL(dots_kernel, dim3(NROWS / 4), dim3(256), 0, stream,
                       q, t, jidx, s10, num);
    hipLaunchKernelGGL(lse_kernel, dim3(64 * NCHUNK), dim3(256), 0, stream,
                       tb, s10, Pm, Ps);
    hipLaunchKernelGGL(finalize_kernel, dim3(1), dim3(256), 0, stream,
                       Pm, Ps, num, out);
}

// Round 2
// 107.753 us; speedup vs baseline: 1.1379x; 1.1379x over previous
//
#include <hip/hip_runtime.h>
#include <stdint.h>

#define NROWS 8192
#define DDIM  128
#define NCHUNK 8
#define CPC   1024            // columns per chunk
#define NTILE 8               // 128-wide tiles per chunk

#define LOG2E 1.4426950408889634f
#define LN2   0.6931471805599453f
#define SCALE (10.0f * LOG2E) // 1/temperature in log2 domain

typedef __bf16 bf16x4 __attribute__((ext_vector_type(4)));
typedef __bf16 bf16x8 __attribute__((ext_vector_type(8)));
typedef float  f32x4  __attribute__((ext_vector_type(4)));

// direct global->LDS, 16B per lane; LDS dest = wave-uniform base + lane*16
__device__ __forceinline__ void gload_lds16(const void* g, void* l) {
    __builtin_amdgcn_global_load_lds(
        (const __attribute__((address_space(1))) void*)g,
        (__attribute__((address_space(3))) void*)l, 16, 0, 0);
}

// ---------------------------------------------------------------- convert t -> bf16
__global__ void convert_kernel(const float* __restrict__ t, __bf16* __restrict__ tb) {
    int idx = blockIdx.x * 256 + threadIdx.x;          // one float4 per thread
    float4 v = reinterpret_cast<const float4*>(t)[idx];
    bf16x4 o;
    o[0] = (__bf16)v.x; o[1] = (__bf16)v.y; o[2] = (__bf16)v.z; o[3] = (__bf16)v.w;
    reinterpret_cast<bf16x4*>(tb)[idx] = o;
}

// ------------------------------------------------- exact fp32 per-row dot products
__global__ void dots_kernel(const float* __restrict__ q, const float* __restrict__ t,
                            const int* __restrict__ jidx,
                            float* __restrict__ s10, float* __restrict__ num) {
    int w    = (blockIdx.x * 256 + threadIdx.x) >> 6;  // one wave per row
    int lane = threadIdx.x & 63;
    int i = w;
    int j = jidx[i];
    float2 qa = reinterpret_cast<const float2*>(q + (size_t)i * DDIM)[lane];
    float2 qb = reinterpret_cast<const float2*>(q + (size_t)j * DDIM)[lane];
    float2 ta = reinterpret_cast<const float2*>(t + (size_t)i * DDIM)[lane];
    float2 tc = reinterpret_cast<const float2*>(t + (size_t)j * DDIM)[lane];
    float dq = qa.x * qb.x + qa.y * qb.y;
    float dt = ta.x * tc.x + ta.y * tc.y;
    #pragma unroll
    for (int off = 32; off; off >>= 1) {
        dq += __shfl_xor(dq, off);
        dt += __shfl_xor(dt, off);
    }
    if (lane == 0) {
        s10[i] = SCALE * dq;
        num[i] = 10.0f * fabsf(dq - dt);
    }
}

// ---------------------------------------------- fused t@t^T + online LSE (bf16 MFMA)
// grid: 64 stripes x 8 chunks. block: 256 thr (4 waves). wave: 32 rows x 128 cols.
// A fragments in registers (constant over tiles); B double-buffered in LDS via
// global_load_lds with pre-swizzled source (linear LDS dest, swizzled ds_read).
__global__ __launch_bounds__(256, 2) void lse_kernel(
    const __bf16* __restrict__ tb, const float* __restrict__ s10,
    float* __restrict__ Pm, float* __restrict__ Ps) {
    __shared__ __bf16 Bt[2][128 * 128];   // 2 x 32 KB

    const int tid    = threadIdx.x;
    const int stripe = blockIdx.x >> 3;
    const int chunk  = blockIdx.x & 7;
    const int row0   = stripe * 128;
    const int col0   = chunk * CPC;

    const int lane = tid & 63;
    const int wid  = tid >> 6;
    const int g    = lane >> 4;    // 16-lane group (k-group for A/B, row-group for D)
    const int lr   = lane & 15;    // row within A-frag / col within B,D-frag
    const int swz  = (lr & 7) << 4;

    // ---- issue stage of tile 0 into buf 0 ASAP
    const int r_st = (tid >> 4);          // 0..15 row handled by this thread (per it-step offset +16)
    const int c_st = tid & 15;            // 16B chunk within row
    const int wave_base = (tid & 0xffffffc0) * 16;   // bytes, wave-uniform
    {
        const char* src = reinterpret_cast<const char*>(tb + (size_t)(col0 + 0 * 128) * DDIM);
        #pragma unroll
        for (int it = 0; it < 8; ++it) {
            int r = r_st + it * 16;
            const char* gsrc = src + ((size_t)r * 16 + (c_st ^ (r & 7))) * 16;
            char* ldst = reinterpret_cast<char*>(&Bt[0][0]) + it * 4096 + wave_base;
            gload_lds16(gsrc, ldst);
        }
    }

    // ---- A fragments direct from global into registers (reused across all tiles)
    bf16x8 af[2][4];
    #pragma unroll
    for (int mf = 0; mf < 2; ++mf) {
        const __bf16* arow = tb + (size_t)(row0 + wid * 32 + mf * 16 + lr) * DDIM + g * 8;
        #pragma unroll
        for (int kk = 0; kk < 4; ++kk)
            af[mf][kk] = *reinterpret_cast<const bf16x8*>(arow + kk * 32);
    }

    // s10 for this lane's 8 output rows (replicated over the 16-lane group)
    float sS[2][4];
    #pragma unroll
    for (int mf = 0; mf < 2; ++mf)
        #pragma unroll
        for (int r = 0; r < 4; ++r)
            sS[mf][r] = s10[row0 + wid * 32 + mf * 16 + g * 4 + r];

    float mrun[2][4], srun[2][4];
    #pragma unroll
    for (int mf = 0; mf < 2; ++mf)
        #pragma unroll
        for (int r = 0; r < 4; ++r) { mrun[mf][r] = -1e30f; srun[mf][r] = 0.0f; }

    for (int tile = 0; tile < NTILE; ++tile) {
        const int cur = tile & 1;
        __syncthreads();   // drains in-flight stage (vmcnt) + protects buffer reuse

        // ---- issue stage of next tile into the other buffer (overlaps compute)
        if (tile + 1 < NTILE) {
            const char* src = reinterpret_cast<const char*>(
                tb + (size_t)(col0 + (tile + 1) * 128) * DDIM);
            #pragma unroll
            for (int it = 0; it < 8; ++it) {
                int r = r_st + it * 16;
                const char* gsrc = src + ((size_t)r * 16 + (c_st ^ (r & 7))) * 16;
                char* ldst = reinterpret_cast<char*>(&Bt[cur ^ 1][0]) + it * 4096 + wave_base;
                gload_lds16(gsrc, ldst);
            }
        }

        // ---- 128x128x128 MFMA on current buffer
        const char* Bb = reinterpret_cast<const char*>(&Bt[cur][0]);
        f32x4 acc[2][8];
        #pragma unroll
        for (int mf = 0; mf < 2; ++mf)
            #pragma unroll
            for (int nf = 0; nf < 8; ++nf)
                acc[mf][nf] = (f32x4){0.f, 0.f, 0.f, 0.f};

        #pragma unroll
        for (int kk = 0; kk < 4; ++kk) {
            bf16x8 bfr[8];
            #pragma unroll
            for (int nf = 0; nf < 8; ++nf) {
                int row = nf * 16 + lr;
                int off = row * 256 + ((g * 16 + kk * 64) ^ swz);
                bfr[nf] = *reinterpret_cast<const bf16x8*>(Bb + off);
            }
            #pragma unroll
            for (int mf = 0; mf < 2; ++mf)
                #pragma unroll
                for (int nf = 0; nf < 8; ++nf)
                    acc[mf][nf] = __builtin_amdgcn_mfma_f32_16x16x32_bf16(
                        af[mf][kk], bfr[nf], acc[mf][nf], 0, 0, 0);
        }

        // ---- online LSE epilogue (log2 domain, per-lane columns only)
        #pragma unroll
        for (int mf = 0; mf < 2; ++mf) {
            #pragma unroll
            for (int r = 0; r < 4; ++r) {
                float sv = sS[mf][r];
                float tv[8];
                #pragma unroll
                for (int nf = 0; nf < 8; ++nf)
                    tv[nf] = fabsf(fmaf(acc[mf][nf][r], -SCALE, sv));
                float tm = fmaxf(fmaxf(fmaxf(tv[0], tv[1]), fmaxf(tv[2], tv[3])),
                                 fmaxf(fmaxf(tv[4], tv[5]), fmaxf(tv[6], tv[7])));
                float m = mrun[mf][r], s = srun[mf][r];
                float nm = fmaxf(m, tm);
                s *= exp2f(m - nm);
                #pragma unroll
                for (int nf = 0; nf < 8; ++nf)
                    s += exp2f(tv[nf] - nm);
                mrun[mf][r] = nm;
                srun[mf][r] = s;
            }
        }
    }

    // ---- merge LSE state across the 16-lane column group, write partials
    #pragma unroll
    for (int mf = 0; mf < 2; ++mf) {
        #pragma unroll
        for (int r = 0; r < 4; ++r) {
            float m = mrun[mf][r], s = srun[mf][r];
            #pragma unroll
            for (int off = 1; off < 16; off <<= 1) {
                float om = __shfl_xor(m, off);
                float os = __shfl_xor(s, off);
                float nm = fmaxf(m, om);
                s = s * exp2f(m - nm) + os * exp2f(om - nm);
                m = nm;
            }
            if (lr == 0) {
                int row = row0 + wid * 32 + mf * 16 + g * 4 + r;
                Pm[row * 8 + chunk] = m;
                Ps[row * 8 + chunk] = s;
            }
        }
    }
}

// ------------------------------------------------------------- final reduction
__global__ void finalize1_kernel(const float* __restrict__ Pm, const float* __restrict__ Ps,
                                 const float* __restrict__ num, float* __restrict__ partial) {
    int tid = threadIdx.x;
    int row = blockIdx.x * 256 + tid;
    float M = -1e30f;
    #pragma unroll
    for (int c = 0; c < 8; ++c) M = fmaxf(M, Pm[row * 8 + c]);
    float S = 0.0f;
    #pragma unroll
    for (int c = 0; c < 8; ++c) S += Ps[row * 8 + c] * exp2f(Pm[row * 8 + c] - M);
    float acc = LN2 * (M + log2f(S)) - num[row];
    __shared__ float red[256];
    red[tid] = acc;
    __syncthreads();
    for (int s2 = 128; s2 > 0; s2 >>= 1) {
        if (tid < s2) red[tid] += red[tid + s2];
        __syncthreads();
    }
    if (tid == 0) partial[blockIdx.x] = red[0];
}

__global__ void finalize2_kernel(const float* __restrict__ partial, float* __restrict__ out) {
    int tid = threadIdx.x;   // 64 threads
    float v = (tid < 32) ? partial[tid] : 0.0f;
    #pragma unroll
    for (int off = 32; off; off >>= 1) v += __shfl_xor(v, off);
    if (tid == 0) out[0] = v / (float)NROWS;
}

extern "C" void kernel_launch(void* const* d_in, const int* in_sizes, int n_in,
                              void* d_out, int out_size, void* d_ws, size_t ws_size,
                              hipStream_t stream) {
    const float* q   = (const float*)d_in[0];
    const float* t   = (const float*)d_in[1];
    const int* jidx  = (const int*)d_in[3];   // d_in[2] = labels (== arange, unused)
    float* out       = (float*)d_out;

    char* ws   = (char*)d_ws;
    __bf16* tb = (__bf16*)ws;                                  // 2 MB
    float* s10 = (float*)(ws + (size_t)NROWS * DDIM * 2);
    float* num = s10 + NROWS;
    float* Pm  = num + NROWS;                                  // 8192*8 floats
    float* Ps  = Pm + NROWS * 8;
    float* par = Ps + NROWS * 8;                               // 32 floats

    hipLaunchKernelGGL(convert_kernel, dim3(NROWS * DDIM / 4 / 256), dim3(256), 0, stream,
                       t, tb);
    hipLaunchKernelGGL(dots_kernel, dim3(NROWS / 4), dim3(256), 0, stream,
                       q, t, jidx, s10, num);
    hipLaunchKernelGGL(lse_kernel, dim3(64 * NCHUNK), dim3(256), 0, stream,
                       tb, s10, Pm, Ps);
    hipLaunchKernelGGL(finalize1_kernel, dim3(NROWS / 256), dim3(256), 0, stream,
                       Pm, Ps, num, par);
    hipLaunchKernelGGL(finalize2_kernel, dim3(1), dim3(64), 0, stream,
                       par, out);
}

// Round 3
// 107.389 us; speedup vs baseline: 1.1418x; 1.0034x over previous
//
#include <hip/hip_runtime.h>
#include <stdint.h>

#define NROWS  8192
#define DDIM   128
#define NCHUNK 16
#define CPC    512            // columns per chunk
#define NTILE  4              // 128-wide tiles per chunk
#define NPHASE 8              // NTILE * 2 K-halves

#define LOG2E 1.4426950408889634f
#define LN2   0.6931471805599453f
#define SCALE (10.0f * LOG2E) // 1/temperature in log2 domain

typedef __bf16 bf16x2 __attribute__((ext_vector_type(2)));
typedef __bf16 bf16x8 __attribute__((ext_vector_type(8)));
typedef float  f32x4  __attribute__((ext_vector_type(4)));

// direct global->LDS, 16B per lane; LDS dest = wave-uniform base + lane*16
__device__ __forceinline__ void gload_lds16(const void* g, void* l) {
    __builtin_amdgcn_global_load_lds(
        (const __attribute__((address_space(1))) void*)g,
        (__attribute__((address_space(3))) void*)l, 16, 0, 0);
}

// ---------------- fused convert(t->bf16) + exact fp32 per-row dot products
// one wave per row i: tb[i] = bf16(t[i]); s10[i] = SCALE*(q_i.q_j);
// num[i] = 10*|q_i.q_j - t_i.t_j|
__global__ void prep_kernel(const float* __restrict__ q, const float* __restrict__ t,
                            const int* __restrict__ jidx, __bf16* __restrict__ tb,
                            float* __restrict__ s10, float* __restrict__ num) {
    int i    = (blockIdx.x * 256 + threadIdx.x) >> 6;
    int lane = threadIdx.x & 63;
    int j = jidx[i];
    float2 ti = reinterpret_cast<const float2*>(t + (size_t)i * DDIM)[lane];
    float2 tj = reinterpret_cast<const float2*>(t + (size_t)j * DDIM)[lane];
    float2 qi = reinterpret_cast<const float2*>(q + (size_t)i * DDIM)[lane];
    float2 qj = reinterpret_cast<const float2*>(q + (size_t)j * DDIM)[lane];
    bf16x2 o;
    o[0] = (__bf16)ti.x; o[1] = (__bf16)ti.y;
    reinterpret_cast<bf16x2*>(tb + (size_t)i * DDIM)[lane] = o;
    float dq = fmaf(qi.x, qj.x, qi.y * qj.y);
    float dt = fmaf(ti.x, tj.x, ti.y * tj.y);
    #pragma unroll
    for (int off = 32; off; off >>= 1) {
        dq += __shfl_xor(dq, off);
        dt += __shfl_xor(dt, off);
    }
    if (lane == 0) {
        s10[i] = SCALE * dq;
        num[i] = 10.0f * fabsf(dq - dt);
    }
}

// ---------------- fused t@t^T + online LSE (bf16 MFMA)
// grid: 64 stripes x 16 chunks = 1024 blocks. block: 256 thr (4 waves).
// wave: 32 rows x 512 cols. B staged in K-halves (16KB) -> 32KB LDS/block
// -> 4 blocks/CU -> 4 waves/SIMD. A fragments live in registers.
__global__ __launch_bounds__(256, 2) void lse_kernel(
    const __bf16* __restrict__ tb, const float* __restrict__ s10,
    float* __restrict__ Pm, float* __restrict__ Ps) {
    __shared__ __bf16 Bt[2][128 * 64];   // 2 x 16 KB

    const int tid    = threadIdx.x;
    const int stripe = blockIdx.x >> 4;
    const int chunk  = blockIdx.x & 15;
    const int row0   = stripe * 128;
    const int col0   = chunk * CPC;

    const int lane = tid & 63;
    const int wid  = tid >> 6;
    const int g    = lane >> 4;    // k-group for A/B, row-group for D
    const int lr   = lane & 15;    // row within A-frag / col within B,D-frag
    const int swz  = (lr & 7) << 4;
    const int wave_base = (tid & 0xffffffc0) * 16;   // bytes, wave-uniform

    const uint4* src4 = reinterpret_cast<const uint4*>(tb);  // 16B chunks, 16/row

    // stage phase p (tile p>>1, K-half p&1) into buffer buf; pre-swizzled source,
    // linear LDS dest (rule #21: inverse-swz source + swz on read)
    auto STAGE = [&](int p, int buf) {
        const int tile = p >> 1, kh = p & 1;
        const int base = (col0 + tile * 128) * 16 + kh * 8;
        #pragma unroll
        for (int it = 0; it < 4; ++it) {
            int idx = it * 256 + tid;
            int r = idx >> 3;
            int c = idx & 7;
            gload_lds16(src4 + base + r * 16 + (c ^ (r & 7)),
                        reinterpret_cast<char*>(&Bt[buf][0]) + it * 4096 + wave_base);
        }
    };

    STAGE(0, 0);   // issue tile0/half0 ASAP

    // A fragments direct from global (constant across all phases)
    bf16x8 af[2][4];
    #pragma unroll
    for (int mf = 0; mf < 2; ++mf) {
        const __bf16* arow = tb + (size_t)(row0 + wid * 32 + mf * 16 + lr) * DDIM + g * 8;
        #pragma unroll
        for (int kk = 0; kk < 4; ++kk)
            af[mf][kk] = *reinterpret_cast<const bf16x8*>(arow + kk * 32);
    }

    float sS[2][4];
    #pragma unroll
    for (int mf = 0; mf < 2; ++mf)
        #pragma unroll
        for (int r = 0; r < 4; ++r)
            sS[mf][r] = s10[row0 + wid * 32 + mf * 16 + g * 4 + r];

    float mrun[2][4], srun[2][4];
    #pragma unroll
    for (int mf = 0; mf < 2; ++mf)
        #pragma unroll
        for (int r = 0; r < 4; ++r) { mrun[mf][r] = -1e30f; srun[mf][r] = 0.0f; }

    f32x4 acc[2][8];

    for (int p = 0; p < NPHASE; ++p) {
        __syncthreads();   // prev readers done + this-phase stage (vmcnt) drained

        if (p + 1 < NPHASE) STAGE(p + 1, (p + 1) & 1);

        if (!(p & 1)) {
            #pragma unroll
            for (int mf = 0; mf < 2; ++mf)
                #pragma unroll
                for (int nf = 0; nf < 8; ++nf)
                    acc[mf][nf] = (f32x4){0.f, 0.f, 0.f, 0.f};
        }

        const char* Bb = reinterpret_cast<const char*>(&Bt[p & 1][0]);
        __builtin_amdgcn_s_setprio(1);
        #pragma unroll
        for (int kk2 = 0; kk2 < 2; ++kk2) {
            const int kk = (p & 1) * 2 + kk2;
            bf16x8 bfr[8];
            #pragma unroll
            for (int nf = 0; nf < 8; ++nf) {
                int off = (nf * 16 + lr) * 128 + ((g * 16 + kk2 * 64) ^ swz);
                bfr[nf] = *reinterpret_cast<const bf16x8*>(Bb + off);
            }
            #pragma unroll
            for (int mf = 0; mf < 2; ++mf)
                #pragma unroll
                for (int nf = 0; nf < 8; ++nf)
                    acc[mf][nf] = __builtin_amdgcn_mfma_f32_16x16x32_bf16(
                        af[mf][kk], bfr[nf], acc[mf][nf], 0, 0, 0);
        }
        __builtin_amdgcn_s_setprio(0);

        if (p & 1) {   // tile complete -> online LSE epilogue (log2 domain)
            #pragma unroll
            for (int mf = 0; mf < 2; ++mf) {
                #pragma unroll
                for (int r = 0; r < 4; ++r) {
                    float sv = sS[mf][r];
                    float tv[8];
                    #pragma unroll
                    for (int nf = 0; nf < 8; ++nf)
                        tv[nf] = fabsf(fmaf(acc[mf][nf][r], -SCALE, sv));
                    float tm = fmaxf(fmaxf(fmaxf(tv[0], tv[1]), fmaxf(tv[2], tv[3])),
                                     fmaxf(fmaxf(tv[4], tv[5]), fmaxf(tv[6], tv[7])));
                    float m = mrun[mf][r];
                    float nm = fmaxf(m, tm);
                    float e[8];
                    #pragma unroll
                    for (int nf = 0; nf < 8; ++nf)
                        e[nf] = exp2f(tv[nf] - nm);
                    float tsum = ((e[0] + e[1]) + (e[2] + e[3])) +
                                 ((e[4] + e[5]) + (e[6] + e[7]));
                    srun[mf][r] = fmaf(srun[mf][r], exp2f(m - nm), tsum);
                    mrun[mf][r] = nm;
                }
            }
        }
    }

    // merge LSE state across the 16-lane column group, write partials
    #pragma unroll
    for (int mf = 0; mf < 2; ++mf) {
        #pragma unroll
        for (int r = 0; r < 4; ++r) {
            float m = mrun[mf][r], s = srun[mf][r];
            #pragma unroll
            for (int off = 1; off < 16; off <<= 1) {
                float om = __shfl_xor(m, off);
                float os = __shfl_xor(s, off);
                float nm = fmaxf(m, om);
                s = s * exp2f(m - nm) + os * exp2f(om - nm);
                m = nm;
            }
            if (lr == 0) {
                int row = row0 + wid * 32 + mf * 16 + g * 4 + r;
                Pm[row * NCHUNK + chunk] = m;
                Ps[row * NCHUNK + chunk] = s;
            }
        }
    }
}

// ------------------------------------------------------------- final reduction
__global__ void finalize1_kernel(const float* __restrict__ Pm, const float* __restrict__ Ps,
                                 const float* __restrict__ num, float* __restrict__ partial) {
    int tid = threadIdx.x;
    int row = blockIdx.x * 256 + tid;
    float M = -1e30f;
    #pragma unroll
    for (int c = 0; c < NCHUNK; ++c) M = fmaxf(M, Pm[row * NCHUNK + c]);
    float S = 0.0f;
    #pragma unroll
    for (int c = 0; c < NCHUNK; ++c) S += Ps[row * NCHUNK + c] * exp2f(Pm[row * NCHUNK + c] - M);
    float acc = LN2 * (M + log2f(S)) - num[row];
    __shared__ float red[256];
    red[tid] = acc;
    __syncthreads();
    for (int s2 = 128; s2 > 0; s2 >>= 1) {
        if (tid < s2) red[tid] += red[tid + s2];
        __syncthreads();
    }
    if (tid == 0) partial[blockIdx.x] = red[0];
}

__global__ void finalize2_kernel(const float* __restrict__ partial, float* __restrict__ out) {
    int tid = threadIdx.x;   // 64 threads
    float v = (tid < 32) ? partial[tid] : 0.0f;
    #pragma unroll
    for (int off = 32; off; off >>= 1) v += __shfl_xor(v, off);
    if (tid == 0) out[0] = v / (float)NROWS;
}

extern "C" void kernel_launch(void* const* d_in, const int* in_sizes, int n_in,
                              void* d_out, int out_size, void* d_ws, size_t ws_size,
                              hipStream_t stream) {
    const float* q   = (const float*)d_in[0];
    const float* t   = (const float*)d_in[1];
    const int* jidx  = (const int*)d_in[3];   // d_in[2] = labels (== arange, unused)
    float* out       = (float*)d_out;

    char* ws   = (char*)d_ws;
    __bf16* tb = (__bf16*)ws;                                  // 2 MB
    float* s10 = (float*)(ws + (size_t)NROWS * DDIM * 2);
    float* num = s10 + NROWS;
    float* Pm  = num + NROWS;                                  // 8192*16 floats
    float* Ps  = Pm + NROWS * NCHUNK;
    float* par = Ps + NROWS * NCHUNK;                          // 32 floats

    hipLaunchKernelGGL(prep_kernel, dim3(NROWS / 4), dim3(256), 0, stream,
                       q, t, jidx, tb, s10, num);
    hipLaunchKernelGGL(lse_kernel, dim3(64 * NCHUNK), dim3(256), 0, stream,
                       tb, s10, Pm, Ps);
    hipLaunchKernelGGL(finalize1_kernel, dim3(NROWS / 256), dim3(256), 0, stream,
                       Pm, Ps, num, par);
    hipLaunchKernelGGL(finalize2_kernel, dim3(1), dim3(64), 0, stream,
                       par, out);
}